// Round 10
// baseline (936.167 us; speedup 1.0000x reference)
//
#include <hip/hip_runtime.h>
#include <hip/hip_bf16.h>
#include <hip/hip_fp16.h>
#include <cmath>

typedef __attribute__((ext_vector_type(8))) short short8_t;
typedef __attribute__((ext_vector_type(4))) float f32x4;

static __device__ __forceinline__ short f2bs(float f) {
    union { __hip_bfloat16 h; short s; } u;
    u.h = __float2bfloat16(f);
    return u.s;
}
static __device__ __forceinline__ float bs2f(unsigned int us) {
    union { float f; unsigned int i; } u;
    u.i = us << 16;
    return u.f;
}
static __device__ __forceinline__ unsigned int pack2bf(float a, float b) {
    return (unsigned int)(unsigned short)f2bs(a) |
           ((unsigned int)(unsigned short)f2bs(b) << 16);
}
// Barrier that waits only on LDS ops (lgkmcnt), NOT vmem.
static __device__ __forceinline__ void lds_barrier() {
    asm volatile("s_waitcnt lgkmcnt(0)\n\ts_barrier" ::: "memory");
}

// ---------------------------------------------------------------------------
// Pack kernel: Wd/W1/W2 -> bf16 MFMA B-fragment order; M = W0t @ We (fp32).
// ---------------------------------------------------------------------------
__global__ void pack_kernel(const float* __restrict__ Wd,
                            const float* __restrict__ W1,
                            const float* __restrict__ W2,
                            const float* __restrict__ W0,
                            const float* __restrict__ We,
                            short* __restrict__ pWd,
                            short* __restrict__ pW1,
                            short* __restrict__ pW2,
                            float* __restrict__ Mb)
{
    const int tid = blockIdx.x * blockDim.x + threadIdx.x;
    const int stride = gridDim.x * blockDim.x;
    for (int i = tid; i < 6 * 32768; i += stride) {
        int c = i >> 15, rem = i & 32767;
        int f = rem >> 9, l = (rem >> 3) & 63, j = rem & 7;
        int kk = f >> 4, nt = f & 15;
        int k = kk * 32 + (l >> 4) * 8 + j;
        int n = nt * 16 + (l & 15);
        pWd[i] = f2bs(Wd[(size_t)c * 32768 + k * 256 + n]);
    }
    for (int i = tid; i < 6 * 16384; i += stride) {
        int c = i >> 14, rem = i & 16383;
        int f = rem >> 9, l = (rem >> 3) & 63, j = rem & 7;
        int kk = f >> 3, nt = f & 7;
        int k = kk * 32 + (l >> 4) * 8 + j;
        int n = nt * 16 + (l & 15);
        pW1[i] = f2bs(W1[(size_t)c * 16384 + k * 128 + n]);
        pW2[i] = f2bs(W2[(size_t)c * 16384 + k * 128 + n]);
    }
    for (int i = tid; i < 6 * 512; i += stride) {
        int c = i >> 9, rem = i & 511;
        int a = rem >> 7, h = rem & 127;
        int t = c % 3;
        float m = 0.f;
        #pragma unroll
        for (int j = 0; j < 4; ++j)
            m = fmaf(W0[t * 16 + a * 4 + j], We[(size_t)c * 512 + j * 128 + h], m);
        Mb[i] = m;
    }
}

// ---------------------------------------------------------------------------
// Convert fp32 -> bf16 (two arrays)
// ---------------------------------------------------------------------------
__global__ void tobf16_kernel(const float* __restrict__ a, const float* __restrict__ b,
                              unsigned short* __restrict__ oa, unsigned short* __restrict__ ob,
                              int n4)
{
    int i = blockIdx.x * blockDim.x + threadIdx.x;
    const int stride = gridDim.x * blockDim.x;
    for (; i < n4; i += stride) {
        float4 va = ((const float4*)a)[i];
        uint2 pa; pa.x = pack2bf(va.x, va.y); pa.y = pack2bf(va.z, va.w);
        ((uint2*)oa)[i] = pa;
        float4 vb = ((const float4*)b)[i];
        uint2 pb; pb.x = pack2bf(vb.x, vb.y); pb.y = pack2bf(vb.z, vb.w);
        ((uint2*)ob)[i] = pb;
    }
}

// ---------------------------------------------------------------------------
// Counting-sort kernels (edges sorted by dst, values scattered).
// ---------------------------------------------------------------------------
__global__ void hist_kernel(const int* __restrict__ ei, int* __restrict__ cnt, int E)
{
    for (int e = blockIdx.x * blockDim.x + threadIdx.x; e < E;
         e += gridDim.x * blockDim.x)
        atomicAdd(&cnt[ei[E + e]], 1);
}

// in-place exclusive scan of 1024-element chunks; block sums -> bsum
__global__ void scan1k_kernel(int* __restrict__ data, int* __restrict__ bsum, int n)
{
    __shared__ int buf[1024];
    const int gid = blockIdx.x * 1024 + threadIdx.x;
    int v = (gid < n) ? data[gid] : 0;
    buf[threadIdx.x] = v;
    __syncthreads();
    for (int off = 1; off < 1024; off <<= 1) {
        int t = (threadIdx.x >= off) ? buf[threadIdx.x - off] : 0;
        __syncthreads();
        buf[threadIdx.x] += t;
        __syncthreads();
    }
    if (gid < n) data[gid] = buf[threadIdx.x] - v;   // exclusive
    if (bsum && threadIdx.x == 1023) bsum[blockIdx.x] = buf[1023];
}

__global__ void scan_add_kernel(int* __restrict__ data, const int* __restrict__ bsum,
                                int* __restrict__ cursor, int n)
{
    const int gid = blockIdx.x * 1024 + threadIdx.x;
    if (gid < n) {
        int v = data[gid] + bsum[blockIdx.x];
        data[gid] = v;
        cursor[gid] = v;
    }
}

__global__ void scatter_kernel(const int* __restrict__ ei, const float* __restrict__ ew,
                               const float4* __restrict__ ea, int* __restrict__ cursor,
                               float* __restrict__ ewp, float4* __restrict__ eap,
                               int* __restrict__ srcp, int* __restrict__ dstp, int E)
{
    for (int e = blockIdx.x * blockDim.x + threadIdx.x; e < E;
         e += gridDim.x * blockDim.x) {
        int d = ei[E + e];
        int p = atomicAdd(&cursor[d], 1);
        ewp[p]  = ew[e];
        eap[p]  = ea[e];
        srcp[p] = ei[e];
        dstp[p] = d;
    }
}

// ---------------------------------------------------------------------------
// Edge kernel (persistent, 512 threads / 8 waves, 64 dst-SORTED edges/tile).
// Wave w owns output cols [32w,32w+32) AND flush rows [8w,8w+8).
// Flush: dst-sorted rows -> fp32 run-reduce, ONE fp16x2 atomic per distinct
// dst per window (~3x fewer atomics than per-edge; R9 showed atomic RMW
// throughput ~72% of L2 ceiling was the wall).
// ---------------------------------------------------------------------------
__global__ __launch_bounds__(512, 2)
void edge_mfma_kernel(
    const unsigned short* __restrict__ xsb,   // bf16 x_src (N,128)
    const int* __restrict__ srcp, const int* __restrict__ dstp,
    const float* __restrict__ ewp, const float4* __restrict__ eap,
    const short* __restrict__ pWd, const float* __restrict__ bd,
    const float* __restrict__ Mb, const float* __restrict__ be,
    __half2* __restrict__ agg, int E, int ntiles,
    float rs, float rstep, float rbeta)
{
    __shared__ short sRbf[64 * 128];   // bf16, swizzled [edge][k], 16KB
    __shared__ __half sSS[64 * 256];   // fp16, swizzled [edge][col], 32KB

    const int t = threadIdx.x;
    const int lane = t & 63;
    const int w = t >> 6;          // 0..7
    const int l15 = lane & 15;
    const int l4 = lane >> 4;

    short8_t bfrag[4][2];          // [kk][i], nt = 2w+i
    #pragma unroll
    for (int kk = 0; kk < 4; ++kk)
        #pragma unroll
        for (int i = 0; i < 2; ++i)
            bfrag[kk][i] = *(const short8_t*)&pWd[((kk * 16 + 2 * w + i) * 64 + lane) * 8];
    float bdv[2];
    #pragma unroll
    for (int i = 0; i < 2; ++i) bdv[i] = bd[(2 * w + i) * 16 + l15];
    const float be0 = be[2 * lane], be1 = be[2 * lane + 1];
    float ma0[4], ma1[4];
    #pragma unroll
    for (int a = 0; a < 4; ++a) {
        ma0[a] = Mb[a * 128 + 2 * lane];
        ma1[a] = Mb[a * 128 + 2 * lane + 1];
    }

    const int stride = gridDim.x;
    int tile = blockIdx.x;
    if (tile >= ntiles) return;

    // ---- prologue: meta + gathers for first tile ----
    float dd_c; int dst_c; float4 ea_c;
    unsigned int gx[8];
    {
        const int e0 = tile << 6;
        int eL = e0 + lane;
        int eLc = eL < E ? eL : E - 1;
        dd_c = ewp[eLc];
        int es = e0 + w * 8 + (lane & 7);
        int esv = es < E ? es : E - 1;
        dst_c = (es < E) ? dstp[esv] : -1;
        int src_c = srcp[esv];
        ea_c = eap[esv];
        #pragma unroll
        for (int r = 0; r < 8; ++r) {
            int srn = __shfl(src_c, r);
            gx[r] = *(const unsigned int*)&xsb[(size_t)srn * 128 + lane * 2];
        }
    }

    for (; tile < ntiles; tile += stride) {
        // ---- phase A: rbf -> sRbf (k-slice), xj -> regs ----
        const float edv = __expf(-dd_c);
        const float dcc = fminf(dd_c, 5.0f);
        const float cutv = 0.5f * (__cosf(dcc * 0.62831853071795864769f) + 1.0f);
        {
            char* base = (char*)sRbf + lane * 256;
            #pragma unroll
            for (int c = 0; c < 2; ++c) {
                short8_t v;
                #pragma unroll
                for (int j = 0; j < 8; ++j) {
                    float mean = rs + (float)(w * 16 + c * 8 + j) * rstep;
                    float diff = edv - mean;
                    v[j] = f2bs(cutv * __expf(-rbeta * diff * diff));
                }
                *(short8_t*)(base + ((w * 32 + c * 16) ^ ((lane & 7) << 4))) = v;
            }
        }
        unsigned int xjr[8];
        #pragma unroll
        for (int r = 0; r < 8; ++r) {
            float ea0 = __shfl(ea_c.x, r), ea1 = __shfl(ea_c.y, r);
            float ea2 = __shfl(ea_c.z, r), ea3 = __shfl(ea_c.w, r);
            unsigned int g = gx[r];
            float x0 = bs2f(g & 0xffffu), x1 = bs2f(g >> 16);
            float o0 = x0 + be0 + ea0 * ma0[0] + ea1 * ma0[1] + ea2 * ma0[2] + ea3 * ma0[3];
            float o1 = x1 + be1 + ea0 * ma1[0] + ea1 * ma1[1] + ea2 * ma1[2] + ea3 * ma1[3];
            xjr[r] = pack2bf(o0, o1);
        }

        lds_barrier();   // bar1: sRbf visible (also fences prev-tile sSS reads)

        // ---- phase B ----
        const int ntile = tile + stride;
        const bool has_next = ntile < ntiles;
        float dd_n = 0.f; int dst_n = -1; int src_n = 0;
        float4 ea_n = {0.f, 0.f, 0.f, 0.f};
        if (has_next) {   // issue next-tile meta loads before any atomics
            const int e0n = ntile << 6;
            int eL = e0n + lane;
            int eLc = eL < E ? eL : E - 1;
            dd_n = ewp[eLc];
            int es = e0n + w * 8 + (lane & 7);
            int esv = es < E ? es : E - 1;
            dst_n = (es < E) ? dstp[esv] : -1;
            src_n = srcp[esv];
            ea_n = eap[esv];
        }
        __builtin_amdgcn_sched_barrier(0);   // pin prefetch issue before GEMM

        // GEMM: ss(64 x 32cols/wave) = rbf(64x128) @ Wd-slice
        f32x4 acc[4][2];
        #pragma unroll
        for (int m = 0; m < 4; ++m) {
            acc[m][0] = (f32x4){0.f, 0.f, 0.f, 0.f};
            acc[m][1] = (f32x4){0.f, 0.f, 0.f, 0.f};
        }
        #pragma unroll
        for (int kk = 0; kk < 4; ++kk) {
            short8_t af[4];
            #pragma unroll
            for (int m = 0; m < 4; ++m) {
                int row = m * 16 + l15;
                int byte = row * 256 + ((kk * 64 + l4 * 16) ^ ((row & 7) << 4));
                af[m] = *(const short8_t*)((const char*)sRbf + byte);
            }
            #pragma unroll
            for (int m = 0; m < 4; ++m)
                #pragma unroll
                for (int i = 0; i < 2; ++i)
                    acc[m][i] = __builtin_amdgcn_mfma_f32_16x16x32_bf16(
                        af[m], bfrag[kk][i], acc[m][i], 0, 0, 0);
        }

        // ss = acc + bd -> sSS fp16 (swizzled [edge][col])
        #pragma unroll
        for (int m = 0; m < 4; ++m)
            #pragma unroll
            for (int i = 0; i < 2; ++i) {
                int col = (2 * w + i) * 16 + l15;
                #pragma unroll
                for (int r = 0; r < 4; ++r) {
                    int row = m * 16 + l4 * 4 + r;
                    int byte = row * 512 + ((col * 2) ^ ((row & 7) << 4));
                    *(__half*)((char*)sSS + byte) = __float2half(acc[m][i][r] + bdv[i]);
                }
            }

        // issue next-tile gathers (acc dead; still before atomics)
        if (has_next) {
            #pragma unroll
            for (int r = 0; r < 8; ++r) {
                int srn = __shfl(src_n, r);
                gx[r] = *(const unsigned int*)&xsb[(size_t)srn * 128 + lane * 2];
            }
        }
        const int dst_f = dst_c;
        dd_c = dd_n; dst_c = dst_n; ea_c = ea_n;

        lds_barrier();   // bar2: sSS visible; sRbf GEMM reads done

        // ---- phase C: segmented run-reduce flush (rows dst-sorted) ----
        {
            float a0 = 0.f, a1 = 0.f;
            int rdst = __shfl(dst_f, 0);
            #pragma unroll
            for (int r = 0; r < 8; ++r) {
                int e = 8 * w + r;
                unsigned int sc = *(const unsigned int*)
                    ((const char*)sSS + e * 512 + ((lane * 4) ^ ((e & 7) << 4)));
                unsigned int sh = *(const unsigned int*)
                    ((const char*)sSS + e * 512 + ((256 + lane * 4) ^ ((e & 7) << 4)));
                float2 scf = __half22float2(*(const __half2*)&sc);
                float2 shf = __half22float2(*(const __half2*)&sh);
                unsigned int g = xjr[r];
                float x0 = bs2f(g & 0xffffu), x1 = bs2f(g >> 16);
                float m0 = fmaxf(fmaf(x0, scf.x, shf.x), 0.0f);
                float m1 = fmaxf(fmaf(x1, scf.y, shf.y), 0.0f);
                int d = __shfl(dst_f, r);   // wave-uniform
                if (d != rdst) {
                    if (rdst >= 0) {
                        __half2 hv = __floats2half2_rn(a0, a1);
                        unsigned int hb;
                        __builtin_memcpy(&hb, &hv, 4);
                        if (hb)
                            unsafeAtomicAdd(agg + (size_t)rdst * 64 + lane, hv);
                    }
                    a0 = 0.f; a1 = 0.f; rdst = d;
                }
                a0 += m0; a1 += m1;
            }
            if (rdst >= 0) {
                __half2 hv = __floats2half2_rn(a0, a1);
                unsigned int hb;
                __builtin_memcpy(&hb, &hv, 4);
                if (hb)
                    unsafeAtomicAdd(agg + (size_t)rdst * 64 + lane, hv);
            }
        }
    }
}

// ---------------------------------------------------------------------------
// Node kernel (persistent): out = relu((agg+x)@W1+b1)@W2+b2 (+prev, relu opt)
// ---------------------------------------------------------------------------
__global__ __launch_bounds__(256)
void node_mfma_kernel(
    const __half2* __restrict__ agg,
    const float* __restrict__ xdf, const unsigned short* __restrict__ xdb,
    const short* __restrict__ pW1, const float* __restrict__ b1,
    const short* __restrict__ pW2, const float* __restrict__ b2,
    float* __restrict__ outf, unsigned short* __restrict__ outb,
    int N, int ntiles, int accumulate, int relu_out)
{
    __shared__ short sA[64 * 128];
    __shared__ short sH[64 * 128];

    const int t = threadIdx.x;
    const int lane = t & 63;
    const int w = t >> 6;
    const int l15 = lane & 15;
    const int l4 = lane >> 4;

    short8_t w1f[4][2], w2f[4][2];
    #pragma unroll
    for (int kk = 0; kk < 4; ++kk)
        #pragma unroll
        for (int p = 0; p < 2; ++p) {
            int nt = 2 * w + p;
            w1f[kk][p] = *(const short8_t*)&pW1[((kk * 8 + nt) * 64 + lane) * 8];
            w2f[kk][p] = *(const short8_t*)&pW2[((kk * 8 + nt) * 64 + lane) * 8];
        }
    float b1v[2], b2v[2];
    #pragma unroll
    for (int p = 0; p < 2; ++p) {
        int col = (2 * w + p) * 16 + l15;
        b1v[p] = b1[col];
        b2v[p] = b2[col];
    }

    for (int tile = blockIdx.x; tile < ntiles; tile += gridDim.x) {
        const int n0 = tile << 6;
        #pragma unroll
        for (int i = 0; i < 4; ++i) {
            int idx = i * 256 + t;
            int row = idx >> 4, c8 = idx & 15;
            int gr = n0 + row; if (gr >= N) gr = N - 1;
            union { float4 f; __half2 h[4]; } ar;
            ar.f = ((const float4*)agg)[(size_t)gr * 16 + c8];
            float xv[8];
            if (xdf) {
                float4 x0 = ((const float4*)xdf)[(size_t)gr * 32 + c8 * 2];
                float4 x1 = ((const float4*)xdf)[(size_t)gr * 32 + c8 * 2 + 1];
                xv[0] = x0.x; xv[1] = x0.y; xv[2] = x0.z; xv[3] = x0.w;
                xv[4] = x1.x; xv[5] = x1.y; xv[6] = x1.z; xv[7] = x1.w;
            } else {
                uint4 xr = ((const uint4*)xdb)[(size_t)gr * 16 + c8];
                xv[0] = bs2f(xr.x & 0xffffu); xv[1] = bs2f(xr.x >> 16);
                xv[2] = bs2f(xr.y & 0xffffu); xv[3] = bs2f(xr.y >> 16);
                xv[4] = bs2f(xr.z & 0xffffu); xv[5] = bs2f(xr.z >> 16);
                xv[6] = bs2f(xr.w & 0xffffu); xv[7] = bs2f(xr.w >> 16);
            }
            short8_t v;
            #pragma unroll
            for (int j = 0; j < 4; ++j) {
                float2 a2 = __half22float2(ar.h[j]);
                v[2 * j]     = f2bs(a2.x + xv[2 * j]);
                v[2 * j + 1] = f2bs(a2.y + xv[2 * j + 1]);
            }
            int byte = row * 256 + ((c8 * 16) ^ ((row & 7) << 4));
            *(short8_t*)((char*)sA + byte) = v;
        }
        lds_barrier();

        f32x4 acc[4][2];
        #pragma unroll
        for (int m = 0; m < 4; ++m) {
            acc[m][0] = (f32x4){0.f, 0.f, 0.f, 0.f};
            acc[m][1] = (f32x4){0.f, 0.f, 0.f, 0.f};
        }
        #pragma unroll
        for (int kk = 0; kk < 4; ++kk) {
            short8_t af[4];
            #pragma unroll
            for (int m = 0; m < 4; ++m) {
                int row = m * 16 + l15;
                int byte = row * 256 + ((kk * 64 + l4 * 16) ^ ((row & 7) << 4));
                af[m] = *(const short8_t*)((const char*)sA + byte);
            }
            #pragma unroll
            for (int m = 0; m < 4; ++m)
                #pragma unroll
                for (int p = 0; p < 2; ++p)
                    acc[m][p] = __builtin_amdgcn_mfma_f32_16x16x32_bf16(
                        af[m], w1f[kk][p], acc[m][p], 0, 0, 0);
        }
        #pragma unroll
        for (int m = 0; m < 4; ++m)
            #pragma unroll
            for (int p = 0; p < 2; ++p) {
                int col = (2 * w + p) * 16 + l15;
                #pragma unroll
                for (int r = 0; r < 4; ++r) {
                    int row = m * 16 + l4 * 4 + r;
                    short hs = f2bs(fmaxf(acc[m][p][r] + b1v[p], 0.f));
                    int byte = row * 256 + ((col * 2) ^ ((row & 7) << 4));
                    *(short*)((char*)sH + byte) = hs;
                }
            }
        lds_barrier();

        f32x4 acc2[4][2];
        #pragma unroll
        for (int m = 0; m < 4; ++m) {
            acc2[m][0] = (f32x4){0.f, 0.f, 0.f, 0.f};
            acc2[m][1] = (f32x4){0.f, 0.f, 0.f, 0.f};
        }
        #pragma unroll
        for (int kk = 0; kk < 4; ++kk) {
            short8_t af[4];
            #pragma unroll
            for (int m = 0; m < 4; ++m) {
                int row = m * 16 + l15;
                int byte = row * 256 + ((kk * 64 + l4 * 16) ^ ((row & 7) << 4));
                af[m] = *(const short8_t*)((const char*)sH + byte);
            }
            #pragma unroll
            for (int m = 0; m < 4; ++m)
                #pragma unroll
                for (int p = 0; p < 2; ++p)
                    acc2[m][p] = __builtin_amdgcn_mfma_f32_16x16x32_bf16(
                        af[m], w2f[kk][p], acc2[m][p], 0, 0, 0);
        }
        #pragma unroll
        for (int m = 0; m < 4; ++m)
            #pragma unroll
            for (int p = 0; p < 2; ++p) {
                int col = (2 * w + p) * 16 + l15;
                #pragma unroll
                for (int r = 0; r < 4; ++r) {
                    int row = n0 + m * 16 + l4 * 4 + r;
                    if (row < N) {
                        float v = acc2[m][p][r] + b2v[p];
                        if (outf) {
                            float* op = &outf[(size_t)row * 128 + col];
                            if (accumulate) v += *op;
                            if (relu_out) v = fmaxf(v, 0.f);
                            *op = v;
                        } else {
                            unsigned short* op = &outb[(size_t)row * 128 + col];
                            if (accumulate) v += bs2f((unsigned int)*op);
                            if (relu_out) v = fmaxf(v, 0.f);
                            *op = (unsigned short)f2bs(v);
                        }
                    }
                }
            }
    }
}

// ---------------------------------------------------------------------------
extern "C" void kernel_launch(void* const* d_in, const int* in_sizes, int n_in,
                              void* d_out, int out_size, void* d_ws, size_t ws_size,
                              hipStream_t stream)
{
    const float* x_lig   = (const float*)d_in[0];
    const float* x_pock  = (const float*)d_in[1];
    const int*   ei_bond = (const int*)d_in[2];
    const float* ew_bond = (const float*)d_in[3];
    const float* ea_bond = (const float*)d_in[4];
    const int*   ei_lp   = (const int*)d_in[5];
    const float* ew_lp   = (const float*)d_in[6];
    const float* ea_lp   = (const float*)d_in[7];
    const int*   ei_pl   = (const int*)d_in[8];
    const float* ew_pl   = (const float*)d_in[9];
    const float* ea_pl   = (const float*)d_in[10];
    const float* W0 = (const float*)d_in[11];
    const float* Wd = (const float*)d_in[12];
    const float* bd = (const float*)d_in[13];
    const float* We = (const float*)d_in[14];
    const float* be = (const float*)d_in[15];
    const float* W1 = (const float*)d_in[16];
    const float* b1 = (const float*)d_in[17];
    const float* W2 = (const float*)d_in[18];
    const float* b2 = (const float*)d_in[19];

    const int H = 128;
    const int N = in_sizes[0] / H;
    const int E_bond = in_sizes[3];
    const int E_lp   = in_sizes[6];
    const int E_pl   = in_sizes[9];

    // ---- workspace layout (256B-aligned bump allocator) ----
    char* wp = (char*)d_ws;
    auto alloc = [&](size_t bytes) -> char* {
        char* r = wp;
        wp += (bytes + 255) & ~(size_t)255;
        return r;
    };
    unsigned short* A   = (unsigned short*)alloc((size_t)N * H * 2);
    unsigned short* Bb  = (unsigned short*)alloc((size_t)N * H * 2);
    unsigned short* C   = (unsigned short*)alloc((size_t)N * H * 2);
    __half*  agg  = (__half*)alloc((size_t)N * H * 2);
    float4*  eapB = (float4*)alloc((size_t)E_bond * 16);
    float4*  eapL = (float4*)alloc((size_t)E_lp * 16);
    float4*  eapP = (float4*)alloc((size_t)E_pl * 16);
    float*   ewpB = (float*)alloc((size_t)E_bond * 4);
    float*   ewpL = (float*)alloc((size_t)E_lp * 4);
    float*   ewpP = (float*)alloc((size_t)E_pl * 4);
    int*     srcB = (int*)alloc((size_t)E_bond * 4);
    int*     srcL = (int*)alloc((size_t)E_lp * 4);
    int*     srcP = (int*)alloc((size_t)E_pl * 4);
    int*     dstB = (int*)alloc((size_t)E_bond * 4);
    int*     dstL = (int*)alloc((size_t)E_lp * 4);
    int*     dstP = (int*)alloc((size_t)E_pl * 4);
    short*   pWd  = (short*)alloc(6 * 32768 * 2);
    short*   pW1s = (short*)alloc(6 * 16384 * 2);
    short*   pW2s = (short*)alloc(6 * 16384 * 2);
    float*   Mb   = (float*)alloc(6 * 512 * 4);
    int*     cnt    = (int*)alloc((size_t)N * 4);
    int*     cursor = (int*)alloc((size_t)N * 4);
    int*     bsum   = (int*)alloc(1024 * 4);

    float* outL = (float*)d_out;
    float* outP = outL + (size_t)N * H;

    const int capE = 2 * 256;
    const int capN = 4 * 256;

    tobf16_kernel<<<512, 256, 0, stream>>>(x_lig, x_pock, A, Bb, N * H / 4);
    pack_kernel<<<256, 256, 0, stream>>>(Wd, W1, W2, W0, We, pWd, pW1s, pW2s, Mb);

    // ---- dst-sort the three edge sets (reused by both layers) ----
    const int nb = (N + 1023) / 1024;
    auto sortset = [&](const int* ei_, const float* ew_, const float* ea_, int E,
                       float* ewp, float4* eap, int* sr716, int* dstp) {
        hipMemsetAsync(cnt, 0, (size_t)N * sizeof(int), stream);
        hist_kernel<<<512, 256, 0, stream>>>(ei_, cnt, E);
        scan1k_kernel<<<nb, 1024, 0, stream>>>(cnt, bsum, N);
        scan1k_kernel<<<1, 1024, 0, stream>>>(bsum, nullptr, nb);
        scan_add_kernel<<<nb, 1024, 0, stream>>>(cnt, bsum, cursor, N);
        scatter_kernel<<<512, 256, 0, stream>>>(ei_, ew_, (const float4*)ea_,
                                                cursor, ewp, eap, sr716, dstp, E);
    };
    sortset(ei_bond, ew_bond, ea_bond, E_bond, ewpB, eapB, srcB, dstB);
    sortset(ei_lp,   ew_lp,   ea_lp,   E_lp,   ewpL, eapL, srcL, dstL);
    sortset(ei_pl,   ew_pl,   ea_pl,   E_pl,   ewpP, eapP, srcP, dstP);

    const double start_d = exp(-5.0);
    const float rs    = (float)start_d;
    const float rstep = (float)((1.0 - start_d) / 127.0);
    const float rbeta = (float)std::pow(2.0 / 128.0 * (1.0 - start_d), -2.0);

    auto conv = [&](const unsigned short* src,
                    const float* xdf, const unsigned short* xdb,
                    const int* srcp, const int* dstp, const float* ewp,
                    const float4* eap, int E,
                    int l, int tt, float* outf, unsigned short* outb,
                    int accum, int relu) {
        hipMemsetAsync(agg, 0, (size_t)N * H * sizeof(__half), stream);
        const int lt = l * 3 + tt;
        const int ntE = (E + 63) / 64;
        const int gE = ntE < capE ? ntE : capE;
        edge_mfma_kernel<<<gE, 512, 0, stream>>>(
            src, srcp, dstp, ewp, eap,
            pWd + (size_t)lt * 32768, bd + (size_t)lt * 256,
            Mb + (size_t)lt * 512, be + (size_t)lt * 128,
            (__half2*)agg, E, ntE, rs, rstep, rbeta);
        const int ntN = (N + 63) / 64;
        const int gN = ntN < capN ? ntN : capN;
        node_mfma_kernel<<<gN, 256, 0, stream>>>(
            (const __half2*)agg, xdf, xdb,
            pW1s + (size_t)lt * 16384, b1 + (size_t)lt * 128,
            pW2s + (size_t)lt * 16384, b2 + (size_t)lt * 128,
            outf, outb, N, ntN, accum, relu);
    };

    // layer 0 (order matters: A is overwritten by bond0's node after lp0+bond0 edges read it)
    conv(A,  x_pock, nullptr, srcL, dstL, ewpL, eapL, E_lp,   0, 1, nullptr, C, 0, 1);
    conv(A,  x_lig,  nullptr, srcB, dstB, ewpB, eapB, E_bond, 0, 0, nullptr, A, 0, 0);
    conv(Bb, x_lig,  nullptr, srcP, dstP, ewpP, eapP, E_pl,   0, 2, nullptr, A, 1, 1);
    // layer 1: lig_bf = A, pock_bf = C
    conv(A, nullptr, A, srcB, dstB, ewpB, eapB, E_bond, 1, 0, outL, nullptr, 0, 0);
    conv(C, nullptr, A, srcP, dstP, ewpP, eapP, E_pl,   1, 2, outL, nullptr, 1, 0);
    conv(A, nullptr, C, srcL, dstL, ewpL, eapL, E_lp,   1, 1, outP, nullptr, 0, 0);
}